// Round 10
// baseline (332.783 us; speedup 1.0000x reference)
//
#include <hip/hip_runtime.h>

#define Hh 64
#define Ww 64
#define Cc 512
#define Bb 16
#define NTOK (1 + Hh * Ww)   // 4097
#define TW 8                 // output pixels per thread along w
#define TH 4                 // output pixels per thread along h

typedef float v2f __attribute__((ext_vector_type(2)));

// ---------------------------------------------------------------------------
// Prep kernel (unchanged): combine w7 + padded w5 + padded w3 + identity into
// one effective 7x7 kernel per channel, stored TRANSPOSED [tap][channel].
// Combine biases, copy cls tokens through.
// ---------------------------------------------------------------------------
__global__ void ppeg_prep(const float* __restrict__ w7, const float* __restrict__ b7,
                          const float* __restrict__ w5, const float* __restrict__ b5,
                          const float* __restrict__ w3, const float* __restrict__ b3,
                          const float* __restrict__ x, float* __restrict__ wt,
                          float* __restrict__ beff, float* __restrict__ out) {
    int idx = blockIdx.x * blockDim.x + threadIdx.x;
    if (idx < Cc * 49) {
        int c = idx / 49, t = idx % 49;
        int r = t / 7, s = t % 7;
        float v = w7[idx];
        if (r >= 1 && r <= 5 && s >= 1 && s <= 5) v += w5[c * 25 + (r - 1) * 5 + (s - 1)];
        if (r >= 2 && r <= 4 && s >= 2 && s <= 4) v += w3[c * 9 + (r - 2) * 3 + (s - 2)];
        if (t == 24) v += 1.0f;               // identity (center tap)
        wt[t * Cc + c] = v;                   // transposed store
    }
    if (idx < Cc) beff[idx] = b7[idx] + b5[idx] + b3[idx];
    if (idx < Bb * Cc) {
        int b = idx / Cc, c = idx % Cc;
        size_t o = (size_t)b * NTOK * Cc + c;
        out[o] = x[o];                        // cls token pass-through
    }
}

// ---------------------------------------------------------------------------
// Conv kernel v11: REGISTER taps, r-chunked, ZERO LDS.
//
// R9 diagnosis (finally localizes the session-long ~26% VALUBusy invariant):
// every variant since v5 read taps from LDS inside the (o,r,s) loop ->
// codegen is {ds_read_b64; s_waitcnt lgkmcnt(0); 8 FMA}: a ~120 cy
// single-outstanding LDS latency serially exposed per 16 cy of math, 196x
// per thread. Per-wave duty ~12%; x2.6 resident waves/SIMD = the measured
// 26-28% VALUBusy in EVERY structure. v7/v8 (window also via ds_read) were
// proportionally worse. R1 -- the only kernel holding taps in registers --
// had the session-high VALUBusy (32%).
//
// v11: outer RUNTIME loop over kernel row r (small code, ~2.5 KB body,
// I-cache-proof). Per r: tap7[7] in registers (14 VGPR, guaranteed fit;
// loaded from the L2-hot 100 KB transposed wt slab); per output row o
// (unrolled): 14-element v2 window loaded direct from global (L1-hot after
// first chunk: a CU's concurrent rows ~24 KB < 32 KB L1), then 56 pk-FMAs
// pure-register. Loads batch under vmcnt; only FMAs depend on loads ->
// duty 60-80% vs 12%. No LDS array, no __syncthreads: occupancy cap
// removed (grid = 32 waves/CU exactly fills the machine).
// Cost: input re-read 7x -- from L1, which was idle.
//
// Kept (proven): float2 channel lanes, chunked XCD swizzle (FETCH at the
// compulsory minimum), nontemporal stores, 256-thread blocks +
// __launch_bounds__(256,2) (the allocator-sane shape).
// ---------------------------------------------------------------------------
__global__ __launch_bounds__(256, 2)
void ppeg_conv(const float* __restrict__ x, const float* __restrict__ wt,
               const float* __restrict__ beff, float* __restrict__ out) {
#pragma clang fp contract(fast)
    const int tx = threadIdx.x;        // channel-pair lane 0..63
    const int ty = threadIdx.y;        // h-strip 0..3 (wave-uniform)

    // --- chunked XCD swizzle (XCD = linear id % 8, x fastest; bijective) ----
    const int L     = blockIdx.x + 32 * (blockIdx.y + 4 * blockIdx.z); // 0..2047
    const int g_lin = (L & 7) * 256 + (L >> 3);
    const int sp    = g_lin & 31;      // spatial block 0..31 within group
    const int g     = g_lin >> 5;      // 0..63 : (cblk, b) group
    const int cb    = (g & 3) * 128;
    const int b     = g >> 2;
    // ------------------------------------------------------------------------

    const int wblk  = sp & 7;
    const int hblk  = sp >> 3;
    const int oh0   = hblk * (TH * 4) + ty * TH;   // first of TH output rows
    const int wbase = wblk * TW;

    const int c0 = cb + 2 * tx;
    const float* xb  = x + ((size_t)b * NTOK + 1) * Cc + c0;  // pixel (0,0)
    const float* wtc = wt + c0;                               // lane's tap base

    const v2f bias = *(const v2f*)&beff[c0];
    v2f acc[TH][TW];
#pragma unroll
    for (int o = 0; o < TH; ++o)
#pragma unroll
        for (int j = 0; j < TW; ++j) acc[o][j] = bias;

    const bool interior = (wblk != 0) && (wblk != 7);

    // Outer RUNTIME loop over kernel rows: 7 register taps per chunk.
    for (int r = 0; r < 7; ++r) {
        v2f tap7[7];
#pragma unroll
        for (int s = 0; s < 7; ++s)
            tap7[s] = *(const v2f*)(wtc + (size_t)(r * 7 + s) * Cc);

#pragma unroll
        for (int o = 0; o < TH; ++o) {
            const int ir = oh0 + o + r - 3;        // wave-uniform
            if (ir < 0 || ir >= Hh) continue;
            const float* xrow = xb + (size_t)ir * (Ww * Cc);
            v2f v[TW + 6];
            if (interior) {
#pragma unroll
                for (int j = 0; j < TW + 6; ++j)
                    v[j] = *(const v2f*)(xrow + (size_t)(wbase - 3 + j) * Cc);
            } else {
#pragma unroll
                for (int j = 0; j < TW + 6; ++j) {
                    const int wc = wbase + j - 3;
                    if (wc >= 0 && wc < Ww)
                        v[j] = *(const v2f*)(xrow + (size_t)wc * Cc);
                    else {
                        v[j].x = 0.0f; v[j].y = 0.0f;
                    }
                }
            }
#pragma unroll
            for (int s = 0; s < 7; ++s)
#pragma unroll
                for (int j = 0; j < TW; ++j)
                    acc[o][j] = tap7[s] * v[j + s] + acc[o][j];
        }
    }

#pragma unroll
    for (int o = 0; o < TH; ++o) {
        float* orow = out + ((size_t)b * NTOK + 1 + (size_t)(oh0 + o) * Ww + wbase) * Cc + c0;
#pragma unroll
        for (int j = 0; j < TW; ++j)
            __builtin_nontemporal_store(acc[o][j], (v2f*)(orow + (size_t)j * Cc));
    }
}

extern "C" void kernel_launch(void* const* d_in, const int* in_sizes, int n_in,
                              void* d_out, int out_size, void* d_ws, size_t ws_size,
                              hipStream_t stream) {
    const float* x  = (const float*)d_in[0];
    const float* w7 = (const float*)d_in[1];
    const float* b7 = (const float*)d_in[2];
    const float* w5 = (const float*)d_in[3];
    const float* b5 = (const float*)d_in[4];
    const float* w3 = (const float*)d_in[5];
    const float* b3 = (const float*)d_in[6];
    float* out = (float*)d_out;

    float* wt   = (float*)d_ws;          // 49*Cc floats, transposed [tap][channel]
    float* beff = wt + 49 * Cc;          // Cc floats

    ppeg_prep<<<(Cc * 49 + 255) / 256, 256, 0, stream>>>(w7, b7, w5, b5, w3, b3,
                                                         x, wt, beff, out);

    // (4 hblk x 8 wblk) x 4 cblk x 16 b = 2048 blocks of 256 threads.
    dim3 grid(32, Cc / 128, Bb);
    dim3 block(64, 4);
    ppeg_conv<<<grid, block, 0, stream>>>(x, wt, beff, out);
}

// Round 11
// 278.818 us; speedup vs baseline: 1.1936x; 1.1936x over previous
//
#include <hip/hip_runtime.h>

#define Hh 64
#define Ww 64
#define Cc 512
#define Bb 16
#define NTOK (1 + Hh * Ww)   // 4097
#define TW 8                 // output pixels per thread along w
#define TH 2                 // output pixels per thread along h

typedef float v4f __attribute__((ext_vector_type(4)));

// ---------------------------------------------------------------------------
// Prep kernel (unchanged): combine w7 + padded w5 + padded w3 + identity into
// one effective 7x7 kernel per channel, stored TRANSPOSED [tap][channel].
// Combine biases, copy cls tokens through.
// ---------------------------------------------------------------------------
__global__ void ppeg_prep(const float* __restrict__ w7, const float* __restrict__ b7,
                          const float* __restrict__ w5, const float* __restrict__ b5,
                          const float* __restrict__ w3, const float* __restrict__ b3,
                          const float* __restrict__ x, float* __restrict__ wt,
                          float* __restrict__ beff, float* __restrict__ out) {
    int idx = blockIdx.x * blockDim.x + threadIdx.x;
    if (idx < Cc * 49) {
        int c = idx / 49, t = idx % 49;
        int r = t / 7, s = t % 7;
        float v = w7[idx];
        if (r >= 1 && r <= 5 && s >= 1 && s <= 5) v += w5[c * 25 + (r - 1) * 5 + (s - 1)];
        if (r >= 2 && r <= 4 && s >= 2 && s <= 4) v += w3[c * 9 + (r - 2) * 3 + (s - 2)];
        if (t == 24) v += 1.0f;               // identity (center tap)
        wt[t * Cc + c] = v;                   // transposed store
    }
    if (idx < Cc) beff[idx] = b7[idx] + b5[idx] + b3[idx];
    if (idx < Bb * Cc) {
        int b = idx / Cc, c = idx % Cc;
        size_t o = (size_t)b * NTOK * Cc + c;
        out[o] = x[o];                        // cls token pass-through
    }
}

// ---------------------------------------------------------------------------
// Conv kernel v12: v10 structure with FLOAT4 channel lanes.
//
// Session audit (R10): time tracks VECTOR-MEMORY INSTRUCTION COUNT across
// all 10 variants (v6 1.15M instrs -> 104us; v9 1.8M -> 123; v11 2.9M ->
// 168; R1 2.3M narrow -> 116), not traffic (67..243 MB at flat time), not
// occupancy (16..73%), not VALU mix. Effective rate ~1 wave-load / ~45 cy
// / CU == an L1-miss/MSHR serialization wall (streaming data thrashes the
// 32KB L1; each 512B load = 4 line-misses queued per CU). v11 falsified
// the LDS-tap-latency theory (removing LDS regressed).
//
// v12 discriminator: halve instruction count at CONSTANT line traffic.
// Lane = 4 channels (dwordx4, 1024 B / 8 lines per wave-instruction).
// Same proven shape economics: TH=2 x TW=8, acc 32 VGPR + window 28 VGPR
// (v6-class live set), 2048 blocks of 256 threads, ~0.8M vmem instrs
// (0.7x v6), address VALU halved. If instr/miss-queue-limited: ~75-88us.
// If flat at ~104: line-bandwidth roofline established.
//
// Kept (proven): LDS tap slab (now 49x256 = 50 KB, ds_read_b128,
// conflict-benign), chunked XCD swizzle (group slab 4 MB = XCD L2),
// nontemporal stores, 256-thread blocks, fp contract for v_pk_fma_f32.
// ---------------------------------------------------------------------------
__global__ __launch_bounds__(256, 2)
void ppeg_conv(const float* __restrict__ x, const float* __restrict__ wt,
               const float* __restrict__ beff, float* __restrict__ out) {
#pragma clang fp contract(fast)
    const int tx = threadIdx.x;        // channel-quad lane 0..63
    const int ty = threadIdx.y;        // h-strip 0..3 (wave-uniform)

    // --- chunked XCD swizzle (XCD = linear id % 8, x fastest; bijective) ----
    const int L     = blockIdx.x + 64 * (blockIdx.y + 2 * blockIdx.z); // 0..2047
    const int g_lin = (L & 7) * 256 + (L >> 3);
    const int sp    = g_lin & 63;      // spatial block 0..63 within group
    const int g     = g_lin >> 6;      // 0..31 : (cblk, b) group
    const int cb    = (g & 1) * 256;
    const int b     = g >> 1;
    // ------------------------------------------------------------------------

    const int wblk  = sp & 7;
    const int hblk  = sp >> 3;         // 0..7
    const int oh0   = hblk * (TH * 4) + ty * TH;   // first of TH output rows
    const int wbase = wblk * TW;

    // Stage the block's 49x256 tap slab into LDS (once), coalesced.
    __shared__ float taps[49][256];
    const int tid = ty * 64 + tx;
    for (int idx = tid; idx < 49 * 256; idx += 256) {
        taps[idx >> 8][idx & 255] = wt[(idx >> 8) * Cc + cb + (idx & 255)];
    }
    __syncthreads();

    const int c0 = cb + 4 * tx;
    const float* xb = x + ((size_t)b * NTOK + 1) * Cc + c0;  // pixel (0,0)

    const v4f bias = *(const v4f*)&beff[c0];
    v4f acc[TH][TW];
#pragma unroll
    for (int o = 0; o < TH; ++o)
#pragma unroll
        for (int j = 0; j < TW; ++j) acc[o][j] = bias;

    const bool interior = (wblk != 0) && (wblk != 7);

    // Stream input rows ir = oh0-3 .. oh0+TH+2. Row k feeds output rows
    // o in [k-6, k] (tap row r = k-o). All indices static after unroll.
#pragma unroll
    for (int k = 0; k < TH + 6; ++k) {
        const int ir = oh0 + k - 3;
        if (ir >= 0 && ir < Hh) {              // wave-uniform (oh0 fixed/wave)
            const float* xrow = xb + (size_t)ir * (Ww * Cc);
            v4f v[TW + 6];
            if (interior) {
#pragma unroll
                for (int j = 0; j < TW + 6; ++j)
                    v[j] = *(const v4f*)(xrow + (size_t)(wbase - 3 + j) * Cc);
            } else {
#pragma unroll
                for (int j = 0; j < TW + 6; ++j) {
                    const int wc = wbase + j - 3;
                    if (wc >= 0 && wc < Ww)
                        v[j] = *(const v4f*)(xrow + (size_t)wc * Cc);
                    else
                        v[j] = (v4f)(0.0f);
                }
            }
#pragma unroll
            for (int o = 0; o < TH; ++o) {
                if (o > k || o < k - 6) continue;   // static after unroll
                const int r = k - o;
#pragma unroll
                for (int s = 0; s < 7; ++s) {
                    const v4f tp = *(const v4f*)&taps[r * 7 + s][4 * tx];
#pragma unroll
                    for (int j = 0; j < TW; ++j)
                        acc[o][j] = tp * v[j + s] + acc[o][j];   // 2x v_pk_fma_f32
                }
            }
        }
    }

#pragma unroll
    for (int o = 0; o < TH; ++o) {
        float* orow = out + ((size_t)b * NTOK + 1 + (size_t)(oh0 + o) * Ww + wbase) * Cc + c0;
#pragma unroll
        for (int j = 0; j < TW; ++j)
            __builtin_nontemporal_store(acc[o][j], (v4f*)(orow + (size_t)j * Cc));
    }
}

extern "C" void kernel_launch(void* const* d_in, const int* in_sizes, int n_in,
                              void* d_out, int out_size, void* d_ws, size_t ws_size,
                              hipStream_t stream) {
    const float* x  = (const float*)d_in[0];
    const float* w7 = (const float*)d_in[1];
    const float* b7 = (const float*)d_in[2];
    const float* w5 = (const float*)d_in[3];
    const float* b5 = (const float*)d_in[4];
    const float* w3 = (const float*)d_in[5];
    const float* b3 = (const float*)d_in[6];
    float* out = (float*)d_out;

    float* wt   = (float*)d_ws;          // 49*Cc floats, transposed [tap][channel]
    float* beff = wt + 49 * Cc;          // Cc floats

    ppeg_prep<<<(Cc * 49 + 255) / 256, 256, 0, stream>>>(w7, b7, w5, b5, w3, b3,
                                                         x, wt, beff, out);

    // (8 hblk x 8 wblk) x 2 cblk x 16 b = 2048 blocks of 256 threads.
    dim3 grid(64, Cc / 256, Bb);
    dim3 block(64, 4);
    ppeg_conv<<<grid, block, 0, stream>>>(x, wt, beff, out);
}